// Round 12
// baseline (885.694 us; speedup 1.0000x reference)
//
#include <hip/hip_runtime.h>
#include <cstddef>
#include <cstdint>

#define NN 2048
#define EE 512
#define HH 8
#define QKVF 1536
#define NSEG 8

typedef __attribute__((ext_vector_type(4))) float f32x4;
typedef __attribute__((ext_vector_type(8))) short s16x8;
typedef __attribute__((ext_vector_type(4))) short s16x4;
typedef __attribute__((ext_vector_type(4))) int i32x4;

static __device__ __forceinline__ unsigned short f2bf(float x) {
  union { float f; unsigned int u; } c; c.f = x;
  unsigned int r = (c.u + 0x7FFFu + ((c.u >> 16) & 1u)) >> 16;
  return (unsigned short)r;
}

#define GLL16(gp, lp) __builtin_amdgcn_global_load_lds( \
    (const __attribute__((address_space(1))) void*)(gp), \
    (__attribute__((address_space(3))) void*)(lp), 16, 0, 0)

// --- prep: weight cvt (b<4096) + linear fp32 mask-weight table (b<8192) + cnt zero ---
__global__ __launch_bounds__(256) void prep(
    const float* __restrict__ s0, const float* __restrict__ s1,
    const float* __restrict__ s2, const float* __restrict__ s3,
    unsigned short* __restrict__ d0, unsigned short* __restrict__ d1,
    unsigned short* __restrict__ d2, unsigned short* __restrict__ d3,
    const int* __restrict__ D, const float* __restrict__ demb,
    const float* __restrict__ dpw, const float* __restrict__ dpb,
    float* __restrict__ wpk4, int* __restrict__ cnt) {
  int b = blockIdx.x;
  if (b < 4096) {
    int j = b * 256 + threadIdx.x;   // 1048576 == 393216+131072+262144+262144
    const float* s; unsigned short* d;
    if (j < 393216) { s = s0; d = d0; }
    else {
      j -= 393216;
      if (j < 131072) { s = s1; d = d1; }
      else {
        j -= 131072;
        if (j < 262144) { s = s2; d = d2; }
        else { j -= 262144; s = s3; d = d3; }
      }
    }
    float4 v = ((const float4*)s)[j];
    s16x4 o;
    o[0] = (short)f2bf(v.x); o[1] = (short)f2bf(v.y);
    o[2] = (short)f2bf(v.z); o[3] = (short)f2bf(v.w);
    ((s16x4*)d)[j] = o;
  } else if (b < 8192) {
    int e = (b - 4096) * 256 + threadIdx.x;  // 2048*512 float4 entries, LINEAR [q][kv/4]
    float ws0 = 0.f, ws1 = 0.f, ws2 = 0.f;
#pragma unroll
    for (int k = 0; k < 8; k++) {
      float pw = dpw[k];
      ws0 += demb[k] * pw; ws1 += demb[8 + k] * pw; ws2 += demb[16 + k] * pw;
    }
    float bb = dpb[0];
    float w0 = __expf(ws0 + bb), w1 = __expf(ws1 + bb), w2 = __expf(ws2 + bb);
    int row = e >> 9, kvq = e & 511;
    i32x4 dd = *(const i32x4*)&D[(size_t)row * NN + kvq * 4];
    f32x4 wv;
#pragma unroll
    for (int i = 0; i < 4; i++) {
      int d = dd[i];
      wv[i] = (d == 0) ? w0 : (d == 1) ? w1 : (d == 2) ? w2 : 0.f;
    }
    ((f32x4*)wpk4)[e] = wv;
  } else {
    int t = threadIdx.x;
    cnt[t] = 0; cnt[t + 256] = 0;   // 2 layers x 256 groups
  }
}

// ---------------- layernorm fp32 in -> bf16 out ----------------
__global__ __launch_bounds__(256) void ln_kernel(const float* __restrict__ x,
    const float* __restrict__ scale, const float* __restrict__ bias,
    unsigned short* __restrict__ out) {
  int row = blockIdx.x;
  int t = threadIdx.x;
  const float* xr = x + (size_t)row * EE;
  float a = xr[t], b = xr[t + 256];
  float s = a + b, q = a * a + b * b;
#pragma unroll
  for (int m = 1; m < 64; m <<= 1) {
    s += __shfl_xor(s, m);
    q += __shfl_xor(q, m);
  }
  __shared__ float ps[4], pq[4];
  int w = t >> 6;
  if ((t & 63) == 0) { ps[w] = s; pq[w] = q; }
  __syncthreads();
  s = ps[0] + ps[1] + ps[2] + ps[3];
  q = pq[0] + pq[1] + pq[2] + pq[3];
  float mu = s * (1.f / EE);
  float var = q * (1.f / EE) - mu * mu;
  float r = rsqrtf(var + 1e-5f);
  unsigned short* orow = out + (size_t)row * EE;
  orow[t] = f2bf((a - mu) * r * scale[t] + bias[t]);
  orow[t + 256] = f2bf((b - mu) * r * scale[t + 256] + bias[t + 256]);
}

// ------- bf16 MFMA GEMM, 64x64 tile, 2-phase dbuf: C = A.B^T + bias -------
template <int RELU, int RES, int OBF>
__global__ __launch_bounds__(256) void gemm_bf(
    const unsigned short* __restrict__ A, const unsigned short* __restrict__ B,
    const float* __restrict__ bias, const float* __restrict__ R,
    void* __restrict__ Cout, int M, int F, int K) {
  __shared__ __attribute__((aligned(16))) unsigned short Al[2][64 * 64];
  __shared__ __attribute__((aligned(16))) unsigned short Bl[2][64 * 64];
  const int t = threadIdx.x;
  const int w = t >> 6, l = t & 63;
  const int fr = l & 15, fs = l >> 4;
  const int bm = blockIdx.y * 64, bf = blockIdx.x * 64;
  const int srow = l >> 3, slot = l & 7;
  const int nk = K >> 6;

  f32x4 acc[4];
  f32x4 zero = {0.f, 0.f, 0.f, 0.f};
#pragma unroll
  for (int j = 0; j < 4; j++) acc[j] = zero;

  auto stage = [&](int kt, int bsel) {
    int k0 = kt * 64;
#pragma unroll
    for (int rnd = 0; rnd < 2; rnd++) {
      int rowblk = w * 2 + rnd;
      int row = rowblk * 8 + srow;
      int koff = (slot * 8) ^ ((row & 7) * 8);
      GLL16(A + (size_t)(bm + row) * K + k0 + koff, &Al[bsel][rowblk * 512]);
      GLL16(B + (size_t)(bf + row) * K + k0 + koff, &Bl[bsel][rowblk * 512]);
    }
  };

  stage(0, 0);
  __syncthreads();
  for (int kt = 0; kt < nk; kt++) {
    const int cur = kt & 1;
    if (kt + 1 < nk) stage(kt + 1, cur ^ 1);
    s16x8 af[2], bg[4][2];
    const int arow = w * 16 + fr;
#pragma unroll
    for (int ks = 0; ks < 2; ks++)
      af[ks] = *(const s16x8*)&Al[cur][arow * 64 + ((ks * 32 + fs * 8) ^ ((arow & 7) * 8))];
#pragma unroll
    for (int ni = 0; ni < 4; ni++)
#pragma unroll
      for (int ks = 0; ks < 2; ks++) {
        int row = 16 * ni + fr;
        bg[ni][ks] = *(const s16x8*)&Bl[cur][row * 64 + ((ks * 32 + fs * 8) ^ ((row & 7) * 8))];
      }
#pragma unroll
    for (int ni = 0; ni < 4; ni++)
#pragma unroll
      for (int ks = 0; ks < 2; ks++)
        acc[ni] = __builtin_amdgcn_mfma_f32_16x16x32_bf16(af[ks], bg[ni][ks], acc[ni], 0, 0, 0);
    __syncthreads();
  }

#pragma unroll
  for (int ni = 0; ni < 4; ni++) {
    int gcol = bf + 16 * ni + fr;
    float bb = bias[gcol];
#pragma unroll
    for (int r = 0; r < 4; r++) {
      int grow = bm + w * 16 + fs * 4 + r;
      float v = acc[ni][r] + bb;
      if (RELU) v = fmaxf(v, 0.f);
      if (RES) v += R[(size_t)grow * F + gcol];
      if (OBF) ((unsigned short*)Cout)[(size_t)grow * F + gcol] = f2bf(v);
      else ((float*)Cout)[(size_t)grow * F + gcol] = v;
    }
  }
}

// ---- MFMA flash attention, split-KV, swapped QK^T, fused combine ----
// S^T = mfma(K,Q): lane holds q=fr, kv=16*ni+fs*4+r (4 consecutive kv -> b64 P pack).
// l via ones-row MFMA. Last seg-block per (bx,h) group combines po/lpart -> attnb.
__global__ __launch_bounds__(256) void attn_mfma(
    const unsigned short* __restrict__ qkv, const float* __restrict__ wpk4,
    float* __restrict__ po, float* __restrict__ lpart,
    unsigned short* __restrict__ attnb, int* __restrict__ cnt) {
  __shared__ __attribute__((aligned(16))) unsigned short Kl[64 * 64];
  __shared__ __attribute__((aligned(16))) unsigned short Vt[66 * 64];
  __shared__ __attribute__((aligned(16))) unsigned short Pl[4][16 * 64];
  __shared__ int done_s;
  const int t = threadIdx.x;
  const int w = t >> 6, l = t & 63;
  const int fr = l & 15, fs = l >> 4;
  const int bx = blockIdx.x, h = blockIdx.y, seg = blockIdx.z;
  const int qrow0 = bx * 64 + w * 16;
  const int kvbase = seg * (NN / NSEG);
  const float C2 = 0.18033688011112042f;  // 0.125 * log2(e)

  if (t < 64) Vt[64 * 64 + t] = 0x3F80;   // ones row (bf16 1.0)

  s16x8 qf[2];
#pragma unroll
  for (int ks = 0; ks < 2; ks++)
    qf[ks] = *(const s16x8*)&qkv[(size_t)(qrow0 + fr) * QKVF + h * 64 + ks * 32 + fs * 8];

  f32x4 o[4], o4;
  f32x4 zero = {0.f, 0.f, 0.f, 0.f};
#pragma unroll
  for (int i = 0; i < 4; i++) o[i] = zero;
  o4 = zero;

  const int krow = t >> 2, kc = (t & 3) * 16;
  const int vkv = (t & 15) * 4, vd = (t >> 4) * 4;
  const unsigned short* kbase = qkv + EE + h * 64;
  const unsigned short* vbase = qkv + 2 * EE + h * 64;
  s16x8 kreg[2];
  s16x4 vreg[4];
#pragma unroll
  for (int i = 0; i < 2; i++)
    kreg[i] = *(const s16x8*)&kbase[(size_t)(kvbase + krow) * QKVF + kc + i * 8];
#pragma unroll
  for (int i = 0; i < 4; i++)
    vreg[i] = *(const s16x4*)&vbase[(size_t)(kvbase + vkv + i) * QKVF + vd];

  for (int ch = 0; ch < NN / NSEG / 64; ch++) {
    __syncthreads();   // previous chunk's LDS reads done (covers ones-row init too)
#pragma unroll
    for (int i = 0; i < 2; i++)
      *(s16x8*)&Kl[krow * 64 + ((kc + i * 8) ^ ((krow & 7) * 8))] = kreg[i];
#pragma unroll
    for (int dj = 0; dj < 4; dj++) {
      int d = vd + dj;
      s16x4 pk;
      pk[0] = vreg[0][dj]; pk[1] = vreg[1][dj]; pk[2] = vreg[2][dj]; pk[3] = vreg[3][dj];
      *(s16x4*)&Vt[d * 64 + (vkv ^ ((d & 7) * 8))] = pk;
    }
    __syncthreads();   // staging visible
    if (ch + 1 < NN / NSEG / 64) {
      int kv0 = kvbase + (ch + 1) * 64;
#pragma unroll
      for (int i = 0; i < 2; i++)
        kreg[i] = *(const s16x8*)&kbase[(size_t)(kv0 + krow) * QKVF + kc + i * 8];
#pragma unroll
      for (int i = 0; i < 4; i++)
        vreg[i] = *(const s16x4*)&vbase[(size_t)(kv0 + vkv + i) * QKVF + vd];
    }

    // QK^T (swapped): S^T[kv][q]; lane: q=fr, kv=16*ni + fs*4 + r
    f32x4 s[4];
#pragma unroll
    for (int ni = 0; ni < 4; ni++) s[ni] = zero;
    __builtin_amdgcn_s_setprio(1);
#pragma unroll
    for (int ni = 0; ni < 4; ni++) {
      int row = 16 * ni + fr;
#pragma unroll
      for (int ks = 0; ks < 2; ks++) {
        s16x8 kf = *(const s16x8*)&Kl[row * 64 + ((ks * 32 + fs * 8) ^ ((row & 7) * 8))];
        s[ni] = __builtin_amdgcn_mfma_f32_16x16x32_bf16(kf, qf[ks], s[ni], 0, 0, 0);
      }
    }
    __builtin_amdgcn_s_setprio(0);
    // softmax numerator, fixed ref (m=0): p = 2^(s*C2) * w; packed b64 P writes
#pragma unroll
    for (int ni = 0; ni < 4; ni++) {
      f32x4 wv = ((const f32x4*)wpk4)[
          (size_t)(qrow0 + fr) * 512 + ((kvbase + ch * 64 + 16 * ni) >> 2) + fs];
      s16x4 pk;
#pragma unroll
      for (int r = 0; r < 4; r++) {
        union { float f; unsigned int u; } c;
        c.f = exp2f(s[ni][r] * C2) * wv[r];
        pk[r] = (short)(c.u >> 16);
      }
      *(s16x4*)&Pl[w][fr * 64 + ((16 * ni + fs * 4) ^ ((fr & 7) * 8))] = pk;
    }
    // PV (+ ones-row tile accumulates l into o4)
    __builtin_amdgcn_s_setprio(1);
#pragma unroll
    for (int ks = 0; ks < 2; ks++) {
      s16x8 pa = *(const s16x8*)&Pl[w][fr * 64 + ((ks * 32 + fs * 8) ^ ((fr & 7) * 8))];
#pragma unroll
      for (int dn = 0; dn < 4; dn++) {
        int row = 16 * dn + fr;
        s16x8 vf = *(const s16x8*)&Vt[row * 64 + ((ks * 32 + fs * 8) ^ ((row & 7) * 8))];
        o[dn] = __builtin_amdgcn_mfma_f32_16x16x32_bf16(pa, vf, o[dn], 0, 0, 0);
      }
      s16x8 vf4 = *(const s16x8*)&Vt[(64 + fr) * 64 + ((ks * 32 + fs * 8) ^ ((fr & 7) * 8))];
      o4 = __builtin_amdgcn_mfma_f32_16x16x32_bf16(pa, vf4, o4, 0, 0, 0);
    }
    __builtin_amdgcn_s_setprio(0);
  }
#pragma unroll
  for (int r = 0; r < 4; r++) {
    int row = qrow0 + fs * 4 + r;
#pragma unroll
    for (int dn = 0; dn < 4; dn++)
      po[((size_t)seg * NN + row) * EE + h * 64 + 16 * dn + fr] = o[dn][r];
    if (fr == 0) lpart[((size_t)seg * NN + row) * 8 + h] = o4[r];
  }

  // ---- fused combine: last seg-block of (bx,h) group divides & writes attnb ----
  __threadfence();           // release my po/lpart writes (device scope)
  __syncthreads();
  if (t == 0) done_s = atomicAdd(&cnt[bx * 8 + h], 1);
  __syncthreads();
  if (done_s == NSEG - 1) {
    __threadfence();         // acquire: invalidate stale cached po/lpart
    int rr = t >> 2;
    int row = bx * 64 + rr;
    int colb = h * 64 + (t & 3) * 16;
    float lsum = 0.f;
#pragma unroll
    for (int sg = 0; sg < NSEG; sg++) lsum += lpart[((size_t)sg * NN + row) * 8 + h];
    float inv = 1.f / lsum;
#pragma unroll
    for (int q4 = 0; q4 < 4; q4++) {
      f32x4 a4 = zero;
#pragma unroll
      for (int sg = 0; sg < NSEG; sg++)
        a4 += *(const f32x4*)&po[((size_t)sg * NN + row) * EE + colb + q4 * 4];
      s16x4 ob;
#pragma unroll
      for (int j = 0; j < 4; j++) ob[j] = (short)f2bf(a4[j] * inv);
      *(s16x4*)&attnb[(size_t)row * EE + colb + q4 * 4] = ob;
    }
  }
}

// ---------------- final logits + softmax (4 rows per block, fp32) ----------------
__global__ __launch_bounds__(256) void logits_kernel(const float* __restrict__ x,
    const float* __restrict__ cw, const float* __restrict__ cb,
    float* __restrict__ out) {
  int t = threadIdx.x;
  int wv = t >> 6, lane = t & 63;
  int row = blockIdx.x * 4 + wv;
  const float* xr = x + (size_t)row * EE;
  int c = lane >> 2, p = lane & 3;
  const float* w = cw + c * EE;
  float s = 0.f;
  for (int e = p * 128; e < p * 128 + 128; e++) s += xr[e] * w[e];
  s += __shfl_xor(s, 1);
  s += __shfl_xor(s, 2);
  __shared__ float lg[4][16];
  if (p == 0) lg[wv][c] = s + cb[c];
  __syncthreads();
  if (lane < 16) {
    float mx = -INFINITY;
#pragma unroll
    for (int k = 0; k < 16; k++) mx = fmaxf(mx, lg[wv][k]);
    float sum = 0.f;
#pragma unroll
    for (int k = 0; k < 16; k++) sum += __expf(lg[wv][k] - mx);
    out[(size_t)row * 16 + lane] = __expf(lg[wv][lane] - mx) / sum;
  }
}

// ---------------- driver ----------------
extern "C" void kernel_launch(void* const* d_in, const int* in_sizes, int n_in,
                              void* d_out, int out_size, void* d_ws, size_t ws_size,
                              hipStream_t stream) {
  const int* D = (const int*)d_in[0];
  const float* x = (const float*)d_in[1];
  const float* demb = (const float*)d_in[2];
  const float* dpw = (const float*)d_in[3];
  const float* dpb = (const float*)d_in[4];
  const float* ln1s = (const float*)d_in[5];
  const float* ln1b = (const float*)d_in[6];
  const float* ipw = (const float*)d_in[7];
  const float* ipb = (const float*)d_in[8];
  const float* ow = (const float*)d_in[9];
  const float* ob = (const float*)d_in[10];
  const float* ln2s = (const float*)d_in[11];
  const float* ln2b = (const float*)d_in[12];
  const float* f1w = (const float*)d_in[13];
  const float* f1b = (const float*)d_in[14];
  const float* f2w = (const float*)d_in[15];
  const float* f2b = (const float*)d_in[16];
  const float* cw = (const float*)d_in[17];
  const float* cb = (const float*)d_in[18];

  char* base = (char*)d_ws;
  float* wpk4 = (float*)base;                                       // @0,  16 MB
  float* xbuf = (float*)(base + (16u << 20));                       // @16, 4 MB
  unsigned short* qkv = (unsigned short*)(base + (20u << 20));      // @20, 6 MB
  unsigned short* xn = (unsigned short*)(base + (26u << 20));       // @26, 2 MB
  unsigned short* attnb = (unsigned short*)(base + (28u << 20));    // @28, 2 MB
  unsigned short* hbuf = (unsigned short*)(base + (30u << 20));     // @30, 4 MB
  unsigned short* ipw_bf = (unsigned short*)(base + (34u << 20));   // @34, 3 MB
  unsigned short* ow_bf = (unsigned short*)(base + (37u << 20));    // @37, 1 MB
  unsigned short* f1w_bf = (unsigned short*)(base + (38u << 20));   // @38, 2 MB
  unsigned short* f2w_bf = (unsigned short*)(base + (40u << 20));   // @40, 2 MB
  float* po = (float*)(base + (42u << 20));                         // @42, 32 MB
  float* lpart = (float*)(base + (74u << 20));                      // @74, 512 KB
  int* cnt = (int*)(base + (75u << 20));                            // @75, 2 KB

  prep<<<8193, 256, 0, stream>>>(ipw, ow, f1w, f2w,
      ipw_bf, ow_bf, f1w_bf, f2w_bf, D, demb, dpw, dpb, wpk4, cnt);

  for (int l = 0; l < 2; l++) {
    const float* xin = (l == 0) ? x : xbuf;
    ln_kernel<<<NN, 256, 0, stream>>>(xin, ln1s + l * EE, ln1b + l * EE, xn);
    gemm_bf<0, 0, 1><<<dim3(24, 32), 256, 0, stream>>>(
        xn, ipw_bf + (size_t)l * 786432, ipb + l * 1536, nullptr, qkv, NN, 1536, 512);
    attn_mfma<<<dim3(32, HH, NSEG), 256, 0, stream>>>(
        qkv, wpk4, po, lpart, attnb, cnt + l * 256);
    gemm_bf<0, 1, 0><<<dim3(8, 32), 256, 0, stream>>>(
        attnb, ow_bf + (size_t)l * 262144, ob + l * EE, xin, xbuf, NN, 512, 512);
    ln_kernel<<<NN, 256, 0, stream>>>(xbuf, ln2s + l * EE, ln2b + l * EE, xn);
    gemm_bf<1, 0, 1><<<dim3(16, 32), 256, 0, stream>>>(
        xn, f1w_bf + (size_t)l * 524288, f1b + l * 1024, nullptr, hbuf, NN, 1024, 512);
    gemm_bf<0, 1, 0><<<dim3(8, 32), 256, 0, stream>>>(
        hbuf, f2w_bf + (size_t)l * 524288, f2b + l * EE, xbuf, xbuf, NN, 512, 1024);
  }
  logits_kernel<<<NN / 4, 256, 0, stream>>>(xbuf, cw, cb, (float*)d_out);
}